// Round 6
// baseline (441.526 us; speedup 1.0000x reference)
//
#include <hip/hip_runtime.h>
#include <hip/hip_bf16.h>

typedef __hip_bfloat16 bf16;
typedef __attribute__((ext_vector_type(8))) short short8;
typedef __attribute__((ext_vector_type(4))) float floatx4;
typedef unsigned long long u64;

#define NVP 10242
#define NV  40962
#define NF  81920
#define VPB 32
#define FPF 2   // faces per wave in k_facegrad

__device__ __forceinline__ unsigned short f2bfbits(float f) {
    bf16 h = __float2bfloat16(f);
    return __builtin_bit_cast(unsigned short, h);
}
__device__ __forceinline__ float bfbits2f(unsigned short u) {
    union { unsigned int i; float f; } cv; cv.i = ((unsigned int)u) << 16;
    return cv.f;
}
// fp8 e4m3 (OCP on gfx950)
__device__ __forceinline__ unsigned short pk_fp8(float a, float b) {
    int p = __builtin_amdgcn_cvt_pk_fp8_f32(a, b, 0, false);
    return (unsigned short)(p & 0xffff);
}
__device__ __forceinline__ unsigned char one_fp8(float a) {
    int p = __builtin_amdgcn_cvt_pk_fp8_f32(a, 0.f, 0, false);
    return (unsigned char)(p & 0xff);
}
__device__ __forceinline__ float f8s0(unsigned int u){return __builtin_amdgcn_cvt_f32_fp8(u,0);}
__device__ __forceinline__ float f8s1(unsigned int u){return __builtin_amdgcn_cvt_f32_fp8(u,1);}

__device__ __forceinline__ void unpack_bf16x8(uint4 q, float o[8]) {
    union { unsigned int u; float f; } cv;
    cv.u = q.x << 16;          o[0] = cv.f;
    cv.u = q.x & 0xffff0000u;  o[1] = cv.f;
    cv.u = q.y << 16;          o[2] = cv.f;
    cv.u = q.y & 0xffff0000u;  o[3] = cv.f;
    cv.u = q.z << 16;          o[4] = cv.f;
    cv.u = q.z & 0xffff0000u;  o[5] = cv.f;
    cv.u = q.w << 16;          o[6] = cv.f;
    cv.u = q.w & 0xffff0000u;  o[7] = cv.f;
}

// ---------------------------------------------------------------------------
// K0 (merged prep): blocks [0,64): coeffsB; [64,384): packG; [384,545): packV.
// Gpk per-face 128 B: dw[0..8] 9 cols | dw[16..24] 9 vals | dw[25..27] EW |
//                     dw[28..30] NS.
// Vpk per-vertex 112 B: dw[0..6] 7 Lcols | dw[7..12] 6 F2Vcols |
//                       dw[14..20] 7 Lvals | dw[21..26] 6 F2Vvals.
// ---------------------------------------------------------------------------
__global__ void k_prep(const float* __restrict__ coeffs,
                       unsigned short* __restrict__ coeffsB,
                       const int* __restrict__ G_cols,
                       const float* __restrict__ G_vals,
                       const float* __restrict__ EW,
                       const float* __restrict__ NS,
                       float* __restrict__ Gpk,
                       const int* __restrict__ L_cols,
                       const float* __restrict__ L_vals,
                       const int* __restrict__ F2V_cols,
                       const float* __restrict__ F2V_vals,
                       float* __restrict__ Vpk) {
    int b = blockIdx.x;
    if (b < 64) {
        int t = b * 256 + threadIdx.x;                 // 0..16383
        int j = t & 7, lane = (t >> 3) & 63, s = t >> 9;
        int ot = s >> 3, kk = s & 7;
        int o  = ot * 16 + (lane & 15);
        int kg = kk * 32 + (lane >> 4) * 8 + j;
        coeffsB[t] = f2bfbits(coeffs[o * 256 + kg]);
    } else if (b < 384) {
        int f = (b - 64) * 256 + threadIdx.x;          // NF/256 = 320 exact
        float r[32];
#pragma unroll
        for (int q = 0; q < 32; ++q) r[q] = 0.f;
#pragma unroll
        for (int d = 0; d < 3; ++d)
#pragma unroll
            for (int j = 0; j < 3; ++j) {
                int idx = (d * NF + f) * 3 + j;
                r[d * 3 + j]      = __int_as_float(G_cols[idx]);
                r[16 + d * 3 + j] = G_vals[idx];
            }
#pragma unroll
        for (int d = 0; d < 3; ++d) {
            r[25 + d] = EW[f * 3 + d];
            r[28 + d] = NS[f * 3 + d];
        }
        float4* dst = (float4*)(Gpk + (size_t)f * 32);
#pragma unroll
        for (int q = 0; q < 8; ++q) dst[q] = ((const float4*)r)[q];
    } else {
        int v = (b - 384) * 256 + threadIdx.x;
        if (v >= NV) return;
        float r[28];
#pragma unroll
        for (int q = 0; q < 28; ++q) r[q] = 0.f;
#pragma unroll
        for (int j = 0; j < 7; ++j) {
            r[j]      = __int_as_float(L_cols[v * 7 + j]);
            r[14 + j] = L_vals[v * 7 + j];
        }
#pragma unroll
        for (int j = 0; j < 6; ++j) {
            r[7 + j]  = __int_as_float(F2V_cols[v * 6 + j]);
            r[21 + j] = F2V_vals[v * 6 + j];
        }
        float4* dst = (float4*)(Vpk + (size_t)v * 28);
#pragma unroll
        for (int q = 0; q < 7; ++q) dst[q] = ((const float4*)r)[q];
    }
}

// ---------------------------------------------------------------------------
// K1: batch-packing transpose. x[b][c][v] fp32 (all 8 b) ->
//   xinp[v][c][b0..7] bf16 (uint4/entry)  and per-batch xin8[b][v][c] fp8.
// xinp rows (1 KB) serve facegrad gathers + vertex f0 for all batches;
// per-batch xin8 rows (64 B, 2.6 MB/batch) stay L2-resident for lap gathers.
// ---------------------------------------------------------------------------
__global__ void __launch_bounds__(256) k_transpose(
    const float* __restrict__ x,
    uint4* __restrict__ xinp, unsigned char* __restrict__ xin8) {
    __shared__ u64 t8 [32][65];
    __shared__ u64 tbL[32][65];
    __shared__ u64 tbH[32][65];
    int v0 = blockIdx.x * 64;
    int tx = threadIdx.x & 63, ty = threadIdx.x >> 6;  // ty 0..3
    for (int half = 0; half < 2; ++half) {
        if (half) __syncthreads();
#pragma unroll
        for (int r = 0; r < 8; ++r) {
            int c  = ty + r * 4;             // 0..31
            int cg = half * 32 + c;
            int v  = v0 + tx;
            u64 p8 = 0, bL = 0, bH = 0;
#pragma unroll
            for (int b = 0; b < 8; ++b) {
                float val = (v < NVP) ? x[((size_t)b * 64 + cg) * NVP + v] : 1.0f;
                p8 |= (u64)one_fp8(val) << (8 * b);
                u64 bf = (u64)f2bfbits(val);
                if (b < 4) bL |= bf << (16 * b);
                else       bH |= bf << (16 * (b - 4));
            }
            t8[c][tx] = p8; tbL[c][tx] = bL; tbH[c][tx] = bH;
        }
        __syncthreads();
        int cc = threadIdx.x & 31;
        int vq = threadIdx.x >> 5;           // 0..7
#pragma unroll
        for (int it = 0; it < 8; ++it) {
            int v  = vq * 8 + it;            // 0..63
            int vg = v0 + v;
            if (vg < NV) {
                size_t idx = (size_t)vg * 64 + half * 32 + cc;
                u64 lo = tbL[cc][v], hi = tbH[cc][v];
                xinp[idx] = make_uint4((unsigned)lo, (unsigned)(lo >> 32),
                                       (unsigned)hi, (unsigned)(hi >> 32));
                u64 p8 = t8[cc][v];
#pragma unroll
                for (int b = 0; b < 8; ++b)
                    xin8[(size_t)b * NV * 64 + idx] =
                        (unsigned char)(p8 >> (8 * b));
            }
        }
    }
}

// ---------------------------------------------------------------------------
// K2: face gradients, all 8 batches per wave-face (the R5 win). 9 uint4
// gathers/face from bf16 xinp (grad inputs now bf16, not fp8) serve all 8
// batches; sched_barrier(0) pins them in flight. Output: per-batch gfi
// (fp8 ew|ns pairs, 128 B rows) so k_vertex keeps its R4 gather shape.
// ---------------------------------------------------------------------------
__global__ void __launch_bounds__(256, 3) k_facegrad(
    const uint4* __restrict__ xinp,
    const float* __restrict__ Gpk,
    unsigned short* __restrict__ gfi) {
    int w  = __builtin_amdgcn_readfirstlane(threadIdx.x >> 6);
    int c  = threadIdx.x & 63;
    int f0 = (blockIdx.x * 4 + w) * FPF;

    // stage A: scalar col loads
    int gc[FPF][9];
#pragma unroll
    for (int i = 0; i < FPF; ++i) {
        const int* ri = (const int*)(Gpk + (size_t)(f0 + i) * 32);
#pragma unroll
        for (int j = 0; j < 9; ++j) gc[i][j] = ri[j];
    }
    // stage B: all 18 uint4 gathers in flight
    uint4 xq[FPF][9];
#pragma unroll
    for (int i = 0; i < FPF; ++i)
#pragma unroll
        for (int j = 0; j < 9; ++j)
            xq[i][j] = xinp[(size_t)gc[i][j] * 64 + c];
    __builtin_amdgcn_sched_barrier(0);
    // stage C: per-batch math + 8 per-batch stores
#pragma unroll
    for (int i = 0; i < FPF; ++i) {
        const float* rf = Gpk + (size_t)(f0 + i) * 32;
        float g0[8], g1[8], g2[8];
#pragma unroll
        for (int b = 0; b < 8; ++b) { g0[b] = 0.f; g1[b] = 0.f; g2[b] = 0.f; }
#pragma unroll
        for (int j = 0; j < 3; ++j) {
            float fa[8], fb[8], fd[8];
            unpack_bf16x8(xq[i][j],     fa);
            unpack_bf16x8(xq[i][3 + j], fb);
            unpack_bf16x8(xq[i][6 + j], fd);
            float va = rf[16 + j], vb = rf[19 + j], vc = rf[22 + j];
#pragma unroll
            for (int b = 0; b < 8; ++b) {
                g0[b] += va * fa[b];
                g1[b] += vb * fb[b];
                g2[b] += vc * fd[b];
            }
        }
        float e0 = rf[25], e1 = rf[26], e2 = rf[27];
        float n0 = rf[28], n1 = rf[29], n2 = rf[30];
#pragma unroll
        for (int b = 0; b < 8; ++b) {
            float ew = g0[b] * e0 + g1[b] * e1 + g2[b] * e2;
            float ns = g0[b] * n0 + g1[b] * n1 + g2[b] * n2;
            gfi[(size_t)b * NF * 64 + (size_t)(f0 + i) * 64 + c] =
                pk_fp8(ew, ns);
        }
    }
}

// ---------------------------------------------------------------------------
// K3: vertex kernel — R4 structure (proven 91 µs). 512 thr, 32 v/block,
// 1-D grid (batch = bid&7 ≡ XCD). Phase 1 explicit 3-stage SoA: scalar cols
// for 4 vertices -> ALL 56 gathers in flight -> vals + math. f0 extracted
// from packed xinp (u32 + shift); lap from per-batch fp8 xin8 (L2-resident);
// grad from per-batch gfi. Phase 2: wave (ot,vh) MFMA. 128-B line stores.
// ---------------------------------------------------------------------------
__global__ void __launch_bounds__(512, 2) k_vertex(
    const unsigned int* __restrict__ xinpw,
    const unsigned char* __restrict__ xin8,
    const float* __restrict__ Vpk,
    const unsigned short* __restrict__ gfi,
    const unsigned short* __restrict__ coeffsB,
    const float* __restrict__ bias,
    float* __restrict__ out) {
    int batch = blockIdx.x & 7;
    int vb    = (blockIdx.x >> 3) * VPB;
    xin8 += (size_t)batch * 64 * NV;
    gfi  += (size_t)batch * 64 * NF;
    out  += (size_t)batch * 64 * NV;
    int bhalf = batch >> 1, bsh = (batch & 1) * 16;

    __shared__ unsigned short feat[VPB * 264];   // 16896 B
    __shared__ float outs[VPB * 65];             // 8320 B
    int w    = __builtin_amdgcn_readfirstlane(threadIdx.x >> 6);  // 0..7
    int lane = threadIdx.x & 63;
    int c    = lane;

    int vcs[4];
#pragma unroll
    for (int i = 0; i < 4; ++i) {
        int v = vb + w * 4 + i;
        vcs[i] = __builtin_amdgcn_readfirstlane(v < NV ? v : NV - 1);
    }
    // stage A: scalar col loads
    int lc[4][7], fc[4][6];
#pragma unroll
    for (int i = 0; i < 4; ++i) {
        const int* ri = (const int*)(Vpk + (size_t)vcs[i] * 28);
#pragma unroll
        for (int j = 0; j < 7; ++j) lc[i][j] = ri[j];
#pragma unroll
        for (int j = 0; j < 6; ++j) fc[i][j] = ri[7 + j];
    }
    // stage B: issue ALL 56 vector gathers
    unsigned int f0u[4], xl[4][7], gg[4][6];
#pragma unroll
    for (int i = 0; i < 4; ++i) {
        f0u[i] = xinpw[((size_t)vcs[i] * 64 + c) * 4 + bhalf];
#pragma unroll
        for (int j = 0; j < 7; ++j)
            xl[i][j] = xin8[(size_t)lc[i][j] * 64 + c];
#pragma unroll
        for (int j = 0; j < 6; ++j)
            gg[i][j] = gfi[(size_t)fc[i][j] * 64 + c];
    }
    __builtin_amdgcn_sched_barrier(0);
    // stage C: val loads + math + feat store
#pragma unroll
    for (int i = 0; i < 4; ++i) {
        const float* rv = Vpk + (size_t)vcs[i] * 28;
        float lap = 0.f;
#pragma unroll
        for (int j = 0; j < 7; ++j)
            lap += rv[14 + j] * f8s0(xl[i][j]);
        float ew = 0.f, ns = 0.f;
#pragma unroll
        for (int j = 0; j < 6; ++j) {
            float val = rv[21 + j];
            ew += val * f8s0(gg[i][j]);
            ns += val * f8s1(gg[i][j]);
        }
        ushort4 p = make_ushort4((unsigned short)(f0u[i] >> bsh),
                                 f2bfbits(lap), f2bfbits(ew), f2bfbits(ns));
        *(ushort4*)&feat[(w * 4 + i) * 264 + c * 4] = p;  // 8B, 2-way (free)
    }
    __syncthreads();

    // ---- phase 2: MFMA. wave w: o-tile = w&3, v-half = w>>2 ----
    int m = lane & 15, quad = lane >> 4;
    int ot = w & 3, vh = w >> 2;
    float bo = bias[ot * 16 + m];
    floatx4 acc = {bo, bo, bo, bo};
#pragma unroll
    for (int kk = 0; kk < 8; ++kk) {
        short8 a = *(const short8*)&feat[(vh * 16 + m) * 264 + kk * 32 + quad * 8];
        short8 bfr = *(const short8*)&coeffsB[((ot * 8 + kk) * 64 + lane) * 8];
        acc = __builtin_amdgcn_mfma_f32_16x16x32_bf16(a, bfr, acc, 0, 0, 0);
    }

    // ---- epilogue: C layout col=lane&15 (o), row=quad*4+reg (v) ----
#pragma unroll
    for (int r = 0; r < 4; ++r)
        outs[(vh * 16 + quad * 4 + r) * 65 + ot * 16 + m] = acc[r];
    __syncthreads();
    int vp = threadIdx.x & 31;          // 32 consecutive v -> 128 B lines
    int og = threadIdx.x >> 5;          // 0..15
    if (vb + vp < NV) {
#pragma unroll
        for (int r = 0; r < 4; ++r) {
            int o2 = og + r * 16;
            out[(size_t)o2 * NV + vb + vp] = outs[vp * 65 + o2];
        }
    }
}

// ---------------------------------------------------------------------------
extern "C" void kernel_launch(void* const* d_in, const int* in_sizes, int n_in,
                              void* d_out, int out_size, void* d_ws, size_t ws_size,
                              hipStream_t stream) {
    const float* x        = (const float*)d_in[0];
    const int*   G_cols   = (const int*)  d_in[2];
    const float* G_vals   = (const float*)d_in[3];
    const int*   L_cols   = (const int*)  d_in[5];
    const float* L_vals   = (const float*)d_in[6];
    const int*   F2V_cols = (const int*)  d_in[8];
    const float* F2V_vals = (const float*)d_in[9];
    const float* EW       = (const float*)d_in[10];
    const float* NS       = (const float*)d_in[11];
    const float* coeffs   = (const float*)d_in[12];
    const float* bias     = (const float*)d_in[13];
    float* out = (float*)d_out;

    char* ws = (char*)d_ws;
    const size_t gpk_bytes  = (size_t)NF * 128;          // 10,485,760
    const size_t vpk_bytes  = (size_t)NV * 112;          //  4,587,744
    const size_t xinp_bytes = (size_t)NV * 64 * 16;      // 41,945,088
    const size_t x8_bytes   = (size_t)8 * NV * 64;       // 20,972,544
    // gfi = 8*NF*64*2 = 83,886,080; total = 161,942,752 B (fits 162.6 MB)

    unsigned short* coeffsB = (unsigned short*)ws;                    // 32 KB
    float* Gpk   = (float*)(ws + 65536);
    float* Vpk   = (float*)(ws + 65536 + gpk_bytes);
    uint4* xinp  = (uint4*)(ws + 65536 + gpk_bytes + vpk_bytes);
    unsigned char* xin8 = (unsigned char*)(ws + 65536 + gpk_bytes + vpk_bytes
                                              + xinp_bytes);
    unsigned short* gfi = (unsigned short*)(ws + 65536 + gpk_bytes + vpk_bytes
                                               + xinp_bytes + x8_bytes);

    k_prep<<<545, 256, 0, stream>>>(coeffs, coeffsB, G_cols, G_vals, EW, NS,
                                    Gpk, L_cols, L_vals, F2V_cols, F2V_vals,
                                    Vpk);
    k_transpose<<<641, 256, 0, stream>>>(x, xinp, xin8);
    k_facegrad<<<NF / (4 * FPF), 256, 0, stream>>>(xinp, Gpk, gfi);
    k_vertex<<<((NV + VPB - 1) / VPB) * 8, 512, 0, stream>>>(
        (const unsigned int*)xinp, xin8, Vpk, gfi, coeffsB, bias, out);
}